// Round 4
// baseline (239.481 us; speedup 1.0000x reference)
//
#include <hip/hip_runtime.h>
#include <hip/hip_bf16.h>
#include <stdint.h>

// Problem constants (AttentionLayer: B=2, L=2048, H=1024, NH=16, HD=64)
#define H_DIM  1024
#define NHEADS 16
#define HDIM   64
#define BATCH  2
#define SEQ    2048
#define MROWS  (BATCH * SEQ)   // 4096
#define QKV_N  (3 * H_DIM)     // 3072
#define QK_LD  (2 * H_DIM)     // qkv2 row stride (Q|K only; V goes to vt)
#define LSTR   72              // padded LDS row stride for P (shorts)
#define QSCALE 0.18033688f     // 0.125 * log2(e)

typedef __attribute__((ext_vector_type(8))) __bf16 bf16x8;
typedef __attribute__((ext_vector_type(4))) float  floatx4;

__device__ __forceinline__ unsigned short f2bf(float f) {
    uint32_t u = __float_as_uint(f);
    u += 0x7fffu + ((u >> 16) & 1u);
    return (unsigned short)(u >> 16);
}
__device__ __forceinline__ unsigned short f2bf_fast(float f) {   // round-half-up (2 ops)
    return (unsigned short)((__float_as_uint(f) + 0x8000u) >> 16);
}

// async global->LDS, 16B per lane; lptr must be wave-uniform [m97 pattern]
__device__ __forceinline__ void async_ld16(const void* g, void* l) {
    __builtin_amdgcn_global_load_lds(
        (const __attribute__((address_space(1))) void*)g,
        (__attribute__((address_space(3))) void*)l, 16, 0, 0);
}

// ---------------------------------------------------------------- cvt fp32 -> bf16
__global__ __launch_bounds__(256) void cvt_f32_bf16(const float4* __restrict__ in,
                                                    ushort4* __restrict__ out, int n4) {
    int i = blockIdx.x * 256 + threadIdx.x;
    if (i < n4) {
        float4 v = in[i];
        ushort4 o;
        o.x = f2bf(v.x); o.y = f2bf(v.y); o.z = f2bf(v.z); o.w = f2bf(v.w);
        out[i] = o;
    }
}

// ---------------------------------------------------------------- GEMM (B^T form)
// C[m][n] = sum_k A[m][k]*B[n][k] + bias[n].  A:[M,K] bf16, B:[N,K] bf16.
// m97-style: global_load_lds width-16 staging, unpadded 128x32 LDS tiles.
// Epilogue when Vt != null (QKV gemm): cols [0,1024) Q -> *QSCALE -> Cb;
// [1024,2048) K -> Cb; [2048,3072) V -> transposed bf16 write to Vt.
// Otherwise Cb (bf16) or Cf (fp32).
__global__ __launch_bounds__(256) void gemm_bt(const unsigned short* __restrict__ A,
                                               const unsigned short* __restrict__ B,
                                               const float* __restrict__ bias,
                                               unsigned short* __restrict__ Cb,
                                               float* __restrict__ Cf,
                                               unsigned short* __restrict__ Vt,
                                               int ldc, int Kdim) {
    __shared__ __align__(16) unsigned short As[128 * 32];
    __shared__ __align__(16) unsigned short Bs[128 * 32];
    const int tid  = threadIdx.x;
    const int lane = tid & 63;
    const int wave = tid >> 6;
    const int waveM = (wave >> 1) * 64;
    const int waveN = (wave & 1) * 64;
    const int bm = blockIdx.y, bn = blockIdx.x;

    floatx4 acc[4][4];
    #pragma unroll
    for (int i = 0; i < 4; ++i)
        #pragma unroll
        for (int j = 0; j < 4; ++j) {
            floatx4 z = {0.f, 0.f, 0.f, 0.f};
            acc[i][j] = z;
        }

    const int c0 = tid, c1 = tid + 256;
    const int r0 = c0 >> 2, kc0 = (c0 & 3) * 8;
    const int r1 = c1 >> 2, kc1 = (c1 & 3) * 8;
    char* asb0 = (char*)As + wave * 1024;
    char* asb1 = (char*)As + 4096 + wave * 1024;
    char* bsb0 = (char*)Bs + wave * 1024;
    char* bsb1 = (char*)Bs + 4096 + wave * 1024;

    const int lr = lane & 15;
    const int lk = (lane >> 4) * 8;

    for (int k0 = 0; k0 < Kdim; k0 += 32) {
        async_ld16(&A[(size_t)(bm * 128 + r0) * Kdim + k0 + kc0], asb0);
        async_ld16(&A[(size_t)(bm * 128 + r1) * Kdim + k0 + kc1], asb1);
        async_ld16(&B[(size_t)(bn * 128 + r0) * Kdim + k0 + kc0], bsb0);
        async_ld16(&B[(size_t)(bn * 128 + r1) * Kdim + k0 + kc1], bsb1);
        __syncthreads();

        bf16x8 af[4], bfr[4];
        #pragma unroll
        for (int i = 0; i < 4; ++i)
            af[i] = *(const bf16x8*)&As[(waveM + i * 16 + lr) * 32 + lk];
        #pragma unroll
        for (int j = 0; j < 4; ++j)
            bfr[j] = *(const bf16x8*)&Bs[(waveN + j * 16 + lr) * 32 + lk];

        #pragma unroll
        for (int i = 0; i < 4; ++i)
            #pragma unroll
            for (int j = 0; j < 4; ++j)
                acc[i][j] = __builtin_amdgcn_mfma_f32_16x16x32_bf16(af[i], bfr[j], acc[i][j], 0, 0, 0);
        __syncthreads();
    }

    // C/D layout: col=lane&15, row=(lane>>4)*4+reg  [m89/m91]
    const int crow0 = bm * 128 + waveM + (lane >> 4) * 4;
    const int ccol0 = bn * 128 + waveN + (lane & 15);
    #pragma unroll
    for (int i = 0; i < 4; ++i)
        #pragma unroll
        for (int j = 0; j < 4; ++j) {
            int col = ccol0 + j * 16;
            float bv = bias[col];
            #pragma unroll
            for (int r = 0; r < 4; ++r) {
                int row = crow0 + i * 16 + r;
                float v = acc[i][j][r] + bv;
                if (Vt) {                                  // QKV gemm epilogue
                    if (col >= 2 * H_DIM) {                // V: transposed write
                        int hd = col - 2 * H_DIM;
                        int bb = row >> 11, kv = row & (SEQ - 1);
                        int hh = hd >> 6,  dd = hd & 63;
                        Vt[((size_t)((bb << 4) + hh) * HDIM + dd) * SEQ + kv] = f2bf(v);
                    } else {
                        float sc = (col < H_DIM) ? QSCALE : 1.f;   // fold softmax scale into Q
                        Cb[(size_t)row * ldc + col] = f2bf(v * sc);
                    }
                } else if (Cb) {
                    Cb[(size_t)row * ldc + col] = f2bf(v);
                } else {
                    Cf[(size_t)row * ldc + col] = v;
                }
            }
        }
}

// ---------------------------------------------------------------- MFMA flash attention
// Grid 1024 (1-D): bh = id&31 (XCD-swizzle: same bh -> same XCD), qt = id>>5.
// Block = 4 waves: i = wave>>1 selects 32 Q rows, j = wave&1 selects KV half (1024 keys).
// No online max (additive partials) -> KV halves combine exactly in LDS at the end.
// K/Vt staged via global_load_lds into unpadded 64x64 tiles with XOR chunk swizzle
// slot(R,c) = R*8 + (c ^ (R&7)); frag reads stay at the 8-lane/group floor.
__global__ __launch_bounds__(256) void attn_mfma(const unsigned short* __restrict__ qkv2,
                                                 const unsigned short* __restrict__ vt,
                                                 unsigned short* __restrict__ ctx) {
    __shared__ __align__(16) unsigned short Ks [2][64 * 64];
    __shared__ __align__(16) unsigned short Vts[2][64 * 64];
    __shared__ __align__(16) unsigned short Ps [4 * 32 * LSTR];   // 18.4KB; reused as fp32 combine buf

    const int tid  = threadIdx.x;
    const int lane = tid & 63;
    const int wave = tid >> 6;
    const int ih   = wave >> 1;          // Q 32-row half
    const int j    = wave & 1;           // KV half
    const int id = blockIdx.x;
    const int bh = id & 31;
    const int qt = id >> 5;
    const int b  = bh >> 4, h = bh & 15;
    const int q0 = qt * 64 + ih * 32;
    const int lq = lane & 15;
    const int g  = lane >> 4;

    unsigned short* Pw  = &Ps[wave * 32 * LSTR];
    unsigned short* Ksj = Ks[j];
    unsigned short* Vtj = Vts[j];

    // Q fragments (already scaled by QSCALE in gemm1): m=lq, k=g*8+..
    bf16x8 qf[2][2];
    #pragma unroll
    for (int s = 0; s < 2; ++s)
        #pragma unroll
        for (int kk = 0; kk < 2; ++kk)
            qf[s][kk] = *(const bf16x8*)&qkv2[(size_t)(b * SEQ + q0 + s * 16 + lq) * QK_LD
                                              + h * HDIM + kk * 32 + g * 8];

    floatx4 acc_o[2][4];
    #pragma unroll
    for (int s = 0; s < 2; ++s)
        #pragma unroll
        for (int dt = 0; dt < 4; ++dt) {
            floatx4 z = {0.f, 0.f, 0.f, 0.f};
            acc_o[s][dt] = z;
        }
    float l_run[2] = {0.f, 0.f};

    const size_t kbase  = (size_t)b * SEQ * QK_LD + H_DIM + (size_t)h * HDIM;
    const size_t vtbase = (size_t)bh * HDIM * SEQ;

    // staging source coords: instr n covers slots (ih*4+n)*64 + lane
    int Rn[4], Cn[4];
    #pragma unroll
    for (int n = 0; n < 4; ++n) {
        int sl = (ih * 4 + n) * 64 + lane;
        Rn[n] = sl >> 3;
        Cn[n] = ((sl & 7) ^ (Rn[n] & 7)) * 8;
    }

    for (int t = 0; t < 16; ++t) {
        const int kv0 = (j * 16 + t) * 64;
        #pragma unroll
        for (int n = 0; n < 4; ++n) {
            async_ld16(&qkv2[kbase + (size_t)(kv0 + Rn[n]) * QK_LD + Cn[n]],
                       (char*)Ksj + (ih * 4 + n) * 1024);
            async_ld16(&vt[vtbase + (size_t)Rn[n] * SEQ + kv0 + Cn[n]],
                       (char*)Vtj + (ih * 4 + n) * 1024);
        }
        __syncthreads();

        // K A-frags (m = kv row jb*16+lq, k = d) and Vt B-frags (n = d row dt*16+lq, k = kv)
        bf16x8 kf[4][2], vf[4][2];
        #pragma unroll
        for (int jb = 0; jb < 4; ++jb)
            #pragma unroll
            for (int kk = 0; kk < 2; ++kk)
                kf[jb][kk] = *(const bf16x8*)&Ksj[((jb * 16 + lq) * 8 + ((kk * 4 + g) ^ (lq & 7))) * 8];
        #pragma unroll
        for (int dt = 0; dt < 4; ++dt)
            #pragma unroll
            for (int kk = 0; kk < 2; ++kk)
                vf[dt][kk] = *(const bf16x8*)&Vtj[((dt * 16 + lq) * 8 + ((kk * 4 + g) ^ (lq & 7))) * 8];

        #pragma unroll
        for (int s = 0; s < 2; ++s) {
            // S^T: lane holds S[q=lq][kv = jb*16 + g*4 + r]
            floatx4 sa[4];
            #pragma unroll
            for (int jb = 0; jb < 4; ++jb) {
                floatx4 z = {0.f, 0.f, 0.f, 0.f};
                sa[jb] = z;
            }
            #pragma unroll
            for (int jb = 0; jb < 4; ++jb)
                #pragma unroll
                for (int kk = 0; kk < 2; ++kk)
                    sa[jb] = __builtin_amdgcn_mfma_f32_16x16x32_bf16(kf[jb][kk], qf[s][kk], sa[jb], 0, 0, 0);

            float ps = 0.f;
            #pragma unroll
            for (int jb = 0; jb < 4; ++jb) {
                float p0 = exp2f(sa[jb][0]), p1 = exp2f(sa[jb][1]);
                float p2 = exp2f(sa[jb][2]), p3 = exp2f(sa[jb][3]);
                ps += (p0 + p1) + (p2 + p3);
                ushort4 pk;
                pk.x = f2bf_fast(p0); pk.y = f2bf_fast(p1);
                pk.z = f2bf_fast(p2); pk.w = f2bf_fast(p3);
                *(ushort4*)&Pw[(s * 16 + lq) * LSTR + jb * 16 + g * 4] = pk;
            }
            ps += __shfl_xor(ps, 16);
            ps += __shfl_xor(ps, 32);
            l_run[s] += ps;

            bf16x8 pf[2];
            #pragma unroll
            for (int kk = 0; kk < 2; ++kk)
                pf[kk] = *(const bf16x8*)&Pw[(s * 16 + lq) * LSTR + kk * 32 + g * 8];
            #pragma unroll
            for (int dt = 0; dt < 4; ++dt)
                #pragma unroll
                for (int kk = 0; kk < 2; ++kk)
                    acc_o[s][dt] = __builtin_amdgcn_mfma_f32_16x16x32_bf16(pf[kk], vf[dt][kk], acc_o[s][dt], 0, 0, 0);
        }
        __syncthreads();
    }

    // in-block combine of the two KV halves (fp32 via LDS), then normalize + store
    float* Osh = (float*)Ps;                  // 4096 floats O + 64 floats l = 16.6KB
    if (j == 1) {
        #pragma unroll
        for (int s = 0; s < 2; ++s) {
            #pragma unroll
            for (int dt = 0; dt < 4; ++dt)
                *(floatx4*)&Osh[(((ih * 2 + s) * 4 + dt) << 8) + lane * 4] = acc_o[s][dt];
            if (g == 0) Osh[4096 + (ih * 2 + s) * 16 + lq] = l_run[s];
        }
    }
    __syncthreads();
    if (j == 0) {
        #pragma unroll
        for (int s = 0; s < 2; ++s) {
            float lt = l_run[s] + Osh[4096 + (ih * 2 + s) * 16 + lq];
            float linv[4];
            #pragma unroll
            for (int r = 0; r < 4; ++r)
                linv[r] = 1.f / __shfl(lt, g * 4 + r);    // lane g*4+r holds row g*4+r
            #pragma unroll
            for (int dt = 0; dt < 4; ++dt) {
                floatx4 oo = *(const floatx4*)&Osh[(((ih * 2 + s) * 4 + dt) << 8) + lane * 4];
                #pragma unroll
                for (int r = 0; r < 4; ++r) {
                    int row = q0 + s * 16 + g * 4 + r;
                    ctx[(size_t)(b * SEQ + row) * H_DIM + h * HDIM + dt * 16 + lq]
                        = f2bf((acc_o[s][dt][r] + oo[r]) * linv[r]);
                }
            }
        }
    }
}

// ---------------------------------------------------------------- launcher
extern "C" void kernel_launch(void* const* d_in, const int* in_sizes, int n_in,
                              void* d_out, int out_size, void* d_ws, size_t ws_size,
                              hipStream_t stream) {
    const float* x     = (const float*)d_in[0];
    const float* w_qkv = (const float*)d_in[1];
    const float* b_qkv = (const float*)d_in[2];
    const float* w_out = (const float*)d_in[3];
    const float* b_out = (const float*)d_in[4];
    float* out = (float*)d_out;

    // workspace (bf16 elements): 4M+3M+1M+8M+4M+4M = 24M shorts = 48 MB
    unsigned short* xb    = (unsigned short*)d_ws;               // 4096*1024
    unsigned short* wqkvb = xb    + (size_t)MROWS * H_DIM;       // 3072*1024
    unsigned short* woutb = wqkvb + (size_t)QKV_N * H_DIM;       // 1024*1024
    unsigned short* qkv2  = woutb + (size_t)H_DIM * H_DIM;       // 4096*2048 (Q|K)
    unsigned short* ctxb  = qkv2  + (size_t)MROWS * QK_LD;       // 4096*1024
    unsigned short* vtb   = ctxb  + (size_t)MROWS * H_DIM;       // 32*64*2048

    cvt_f32_bf16<<<MROWS * H_DIM / 1024, 256, 0, stream>>>((const float4*)x,     (ushort4*)xb,    MROWS * H_DIM / 4);
    cvt_f32_bf16<<<QKV_N * H_DIM / 1024, 256, 0, stream>>>((const float4*)w_qkv, (ushort4*)wqkvb, QKV_N * H_DIM / 4);
    cvt_f32_bf16<<<H_DIM * H_DIM / 1024, 256, 0, stream>>>((const float4*)w_out, (ushort4*)woutb, H_DIM * H_DIM / 4);

    // qkv2 = x @ w_qkv^T + b_qkv  (Q (scaled)|K -> qkv2, V -> vtb transposed)
    gemm_bt<<<dim3(QKV_N / 128, MROWS / 128), 256, 0, stream>>>(xb, wqkvb, b_qkv, qkv2, nullptr, vtb, QK_LD, H_DIM);

    // flash attention -> ctx bf16 [4096, 1024]
    attn_mfma<<<(SEQ / 64) * BATCH * NHEADS, 256, 0, stream>>>(qkv2, vtb, ctxb);

    // out = ctx @ w_out^T + b_out -> fp32 [4096, 1024]
    gemm_bt<<<dim3(H_DIM / 128, MROWS / 128), 256, 0, stream>>>(ctxb, woutb, b_out, nullptr, out, nullptr, H_DIM, H_DIM);
}